// Round 5
// baseline (232.277 us; speedup 1.0000x reference)
//
#include <hip/hip_runtime.h>
#include <hip/hip_bf16.h>

#define TPB 256
#define HW 4096
#define NB 4096   // 12-bit radix on key bits 30..19

typedef unsigned int u32;
typedef unsigned long long u64;

__global__ void __launch_bounds__(TPB)
topk_blend_kernel(const float* __restrict__ x, const float* __restrict__ taup,
                  const int* __restrict__ kp, float* __restrict__ out)
{
    __shared__ u32 hist[NB];            // 16 KiB; reused as candidate-pack storage
    __shared__ u32 waveTot[4];
    __shared__ u32 sh_b, sh_k1, sh_cnt, sh_pstar;

    const int tid  = threadIdx.x;
    const int lane = tid & 63;
    const int wv   = tid >> 6;
    const int row  = blockIdx.x;

    const float4* xr  = reinterpret_cast<const float4*>(x + (size_t)row * HW);
    float4*       orw = reinterpret_cast<float4*>(out + (size_t)row * HW);

    // ---- clear histogram (b128 stores) + counter ----
    uint4* h4 = reinterpret_cast<uint4*>(hist);
    const uint4 z4 = make_uint4(0u, 0u, 0u, 0u);
#pragma unroll
    for (int j = 0; j < NB / 4 / TPB; ++j) h4[tid + j * TPB] = z4;
    if (tid == 0) sh_cnt = 0;

    // ---- load 16 elements/thread as raw bits (coalesced 4x float4) ----
    u32 r[16];
#pragma unroll
    for (int j = 0; j < 4; ++j) {
        float4 v = xr[tid + j * TPB];
        r[4 * j + 0] = __float_as_uint(v.x);
        r[4 * j + 1] = __float_as_uint(v.y);
        r[4 * j + 2] = __float_as_uint(v.z);
        r[4 * j + 3] = __float_as_uint(v.w);
    }
    const u32  K   = (u32)(*kp);
    const float tau = *taup;
    __syncthreads();                                   // A: clear done

    if (K >= HW) {                                     // reference returns x verbatim
#pragma unroll
        for (int j = 0; j < 4; ++j) {
            float4 o;
            o.x = __uint_as_float(r[4 * j + 0]);
            o.y = __uint_as_float(r[4 * j + 1]);
            o.z = __uint_as_float(r[4 * j + 2]);
            o.w = __uint_as_float(r[4 * j + 3]);
            orw[tid + j * TPB] = o;
        }
        return;
    }

    // ---- single histogram pass ----
#pragma unroll
    for (int e = 0; e < 16; ++e)
        atomicAdd(&hist[(r[e] & 0x7fffffffu) >> 19], 1u);
    __syncthreads();                                   // B: histogram done

    // ---- parallel crossing search ----
    u32 hh[16];
    {
        uint4 a0 = h4[tid * 4 + 0], a1 = h4[tid * 4 + 1];
        uint4 a2 = h4[tid * 4 + 2], a3 = h4[tid * 4 + 3];
        hh[0]=a0.x; hh[1]=a0.y; hh[2]=a0.z;  hh[3]=a0.w;
        hh[4]=a1.x; hh[5]=a1.y; hh[6]=a1.z;  hh[7]=a1.w;
        hh[8]=a2.x; hh[9]=a2.y; hh[10]=a2.z; hh[11]=a2.w;
        hh[12]=a3.x;hh[13]=a3.y;hh[14]=a3.z; hh[15]=a3.w;
    }
    u32 s = 0;
#pragma unroll
    for (int j = 0; j < 16; ++j) s += hh[j];

    u32 suf = s;                                       // wave suffix-inclusive scan
#pragma unroll
    for (int d = 1; d < 64; d <<= 1) {
        u32 t = __shfl_down(suf, d, 64);
        if (lane + d < 64) suf += t;
    }
    if (lane == 0) waveTot[wv] = suf;
    __syncthreads();                                   // C
    u32 above = suf - s;
#pragma unroll
    for (int w2 = 0; w2 < 4; ++w2)
        if (w2 > wv) above += waveTot[w2];

    if (above < K && above + s >= K) {                 // exactly one thread
        u32 c = above;
        int fb = -1; u32 kk = 0;
#pragma unroll
        for (int bi = 15; bi >= 0; --bi) {
            u32 hb = hh[bi];
            if (fb < 0) {
                if (c + hb >= K) { fb = bi; kk = K - c; }
                else c += hb;
            }
        }
        sh_b  = (u32)(tid * 16 + fb);
        sh_k1 = kk;
    }
    __syncthreads();                                   // D: hist free for reuse

    const u32 bstar = sh_b;
    const u32 k1    = sh_k1;

    // ---- gather crossing-bin candidates into reused hist (wave-aggregated) ----
    u32* cand = hist;
#pragma unroll
    for (int e = 0; e < 16; ++e) {
        u32 key = r[e] & 0x7fffffffu;
        bool inb = ((key >> 19) == bstar);
        u64 m = __ballot(inb);
        if (m) {
            int leader = (int)(__ffsll((long long)m) - 1);
            u32 base = 0;
            if (lane == leader) base = atomicAdd(&sh_cnt, (u32)__popcll(m));
            base = __shfl(base, leader, 64);
            if (inb) {
                int j = e >> 2, l = e & 3;
                u32 idx  = (u32)((((j * TPB + tid) << 2) | l));
                u32 pack = ((key & 0x7ffffu) << 12) | (4095u - idx);
                cand[base + (u32)__popcll(m & ((1ull << lane) - 1ull))] = pack;
            }
        }
    }
    __syncthreads();                                   // E: candidates gathered

    const u32 ceq = sh_cnt;
    // ---- exact rank: k1-th largest pack (packs unique) ----
    for (u32 i = tid; i < ceq; i += TPB) {
        u32 p  = cand[i];
        u32 rk = 0;
        for (u32 j2 = 0; j2 < ceq; ++j2)
            rk += (cand[j2] > p) ? 1u : 0u;
        if (rk == k1 - 1u) sh_pstar = p;
    }
    __syncthreads();                                   // F
    const u32 pstar = sh_pstar;

    // ---- epilogue: blend + coalesced store ----
    const float om = 1.0f - tau;
#pragma unroll
    for (int j = 0; j < 4; ++j) {
        float4 o;
        float* po = reinterpret_cast<float*>(&o);
#pragma unroll
        for (int l = 0; l < 4; ++l) {
            int e = 4 * j + l;
            u32 rb   = r[e];
            u32 key  = rb & 0x7fffffffu;
            u32 bin  = key >> 19;
            u32 idx  = (u32)((((j * TPB + tid) << 2) | l));
            u32 pack = ((key & 0x7ffffu) << 12) | (4095u - idx);
            bool keep = (bin > bstar) || (bin == bstar && pack >= pstar);
            float xv = __uint_as_float(rb);
            po[l] = keep ? (xv * tau + xv * om) : (xv * om);
        }
        orw[tid + j * TPB] = o;
    }
}

extern "C" void kernel_launch(void* const* d_in, const int* in_sizes, int n_in,
                              void* d_out, int out_size, void* d_ws, size_t ws_size,
                              hipStream_t stream)
{
    (void)n_in; (void)out_size; (void)d_ws; (void)ws_size;
    const float* x   = (const float*)d_in[0];
    const float* tau = (const float*)d_in[1];
    const int*   kp  = (const int*)d_in[2];
    float*       out = (float*)d_out;
    const int nrows  = in_sizes[0] / HW;   // 32*256 = 8192 rows
    topk_blend_kernel<<<nrows, TPB, 0, stream>>>(x, tau, kp, out);
}